// Round 3
// baseline (153.160 us; speedup 1.0000x reference)
//
#include <hip/hip_runtime.h>
#include <math.h>

#define NG 512
#define HH 256
#define WW 256

__device__ __forceinline__ float softplus_f(float x) {
    // log(1+exp(x)); stable for large |x|
    if (x > 20.0f) return x;
    if (x < -20.0f) return expf(x);
    return log1pf(expf(x));
}

__device__ __forceinline__ float sigmoid_f(float x) {
    return 1.0f / (1.0f + expf(-x));
}

// Precompute per-gaussian parameters: [mx, my, a, b] [c, opac, r, g] [bcol, 0,0,0]
// stride 12 floats (3x float4) per gaussian.
__global__ void prep_kernel(const float* __restrict__ means,
                            const float* __restrict__ chol,
                            const float* __restrict__ rgbl,
                            const float* __restrict__ opl,
                            float* __restrict__ params) {
    int n = blockIdx.x * blockDim.x + threadIdx.x;
    if (n >= NG) return;
    float L11 = softplus_f(chol[3*n + 0]);
    float L21 = chol[3*n + 1];
    float L22 = softplus_f(chol[3*n + 2]);
    float s00 = L11 * L11;
    float s01 = L11 * L21;
    float s11 = L21 * L21 + L22 * L22;
    float d  = L11 * L22;
    float det = d * d;
    float inv = 1.0f / det;
    float a =  s11 * inv;
    float b = -s01 * inv;
    float c =  s00 * inv;
    float opac = sigmoid_f(opl[n]);
    float r  = sigmoid_f(rgbl[3*n + 0]);
    float g  = sigmoid_f(rgbl[3*n + 1]);
    float bb = sigmoid_f(rgbl[3*n + 2]);
    float* p = params + 12 * n;
    p[0] = means[2*n + 0];
    p[1] = means[2*n + 1];
    p[2] = a;
    p[3] = b;
    p[4] = c;
    p[5] = opac;
    p[6] = r;
    p[7] = g;
    p[8] = bb;
    p[9] = 0.0f; p[10] = 0.0f; p[11] = 0.0f;
}

// One thread per pixel; one block per image row (256 threads).
// Inner loop over all 512 gaussians with running transmittance product.
__global__ __launch_bounds__(WW, 1)
void render_kernel(const float* __restrict__ params, float* __restrict__ out) {
    const int w = threadIdx.x;
    const int h = blockIdx.x;
    const float px = (float)w + 0.5f;
    const float py = (float)h + 0.5f;

    float T = 1.0f;
    float ir = 0.f, ig = 0.f, ib = 0.f, wsum = 0.f;
    float xr = 0.f, xg = 0.f, xb = 0.f;
    float yr = 0.f, yg = 0.f, yb = 0.f;
    float qr = 0.f, qg = 0.f, qb = 0.f;

    const float4* __restrict__ g4 = (const float4*)params;

    #pragma unroll 4
    for (int n = 0; n < NG; ++n) {
        float4 P0 = g4[3*n + 0];   // mx, my, a, b
        float4 P1 = g4[3*n + 1];   // c, opac, r, g
        float4 P2 = g4[3*n + 2];   // bcol, -, -, -
        float dX = P0.x - px;
        float dY = P0.y - py;
        float a = P0.z, b = P0.w, c = P1.x, opac = P1.y;
        float gx = a * dX + b * dY;
        float gy = b * dX + c * dY;
        float s  = 0.5f * (dX * gx + dY * gy);
        float e  = __expf(-s);
        float alpha = fminf(opac * e, 0.999f);
        float vis = alpha * T;
        T = T - alpha * T;
        wsum += vis;
        float r = P1.z, g = P1.w, bb = P2.x;
        ir += vis * r;  ig += vis * g;  ib += vis * bb;
        float vgx = vis * gx;
        float vgy = vis * gy;
        xr += vgx * r;  xg += vgx * g;  xb += vgx * bb;
        yr += vgy * r;  yg += vgy * g;  yb += vgy * bb;
        float q  = gx * gy - b;
        float vq = vis * q;
        qr += vq * r;   qg += vq * g;   qb += vq * bb;
    }

    const int HW = HH * WW;
    const int p  = h * WW + w;

    // render: [c][h][w]
    out[0*HW + p] = ir;
    out[1*HW + p] = ig;
    out[2*HW + p] = ib;
    // img: [h][w][c]
    float* img = out + 3*HW;
    img[3*p + 0] = ir; img[3*p + 1] = ig; img[3*p + 2] = ib;
    // wsum: [h][w]
    out[6*HW + p] = wsum;
    // dx_img
    float* dx = out + 7*HW;
    dx[3*p + 0] = xr; dx[3*p + 1] = xg; dx[3*p + 2] = xb;
    // dy_img
    float* dy = out + 10*HW;
    dy[3*p + 0] = yr; dy[3*p + 1] = yg; dy[3*p + 2] = yb;
    // dxy_img
    float* dq = out + 13*HW;
    dq[3*p + 0] = qr; dq[3*p + 1] = qg; dq[3*p + 2] = qb;
}

extern "C" void kernel_launch(void* const* d_in, const int* in_sizes, int n_in,
                              void* d_out, int out_size, void* d_ws, size_t ws_size,
                              hipStream_t stream) {
    const float* means = (const float*)d_in[0];
    const float* chol  = (const float*)d_in[1];
    const float* rgbl  = (const float*)d_in[2];
    const float* opl   = (const float*)d_in[3];
    float* out = (float*)d_out;
    float* params = (float*)d_ws;   // 512 * 12 floats = 24 KB

    prep_kernel<<<dim3((NG + 255) / 256), dim3(256), 0, stream>>>(means, chol, rgbl, opl, params);
    render_kernel<<<dim3(HH), dim3(WW), 0, stream>>>(params, out);
}

// Round 4
// 90.496 us; speedup vs baseline: 1.6924x; 1.6924x over previous
//
#include <hip/hip_runtime.h>
#include <math.h>

#define NG 512
#define HH 256
#define WW 256
#define CHUNKS 8
#define CG (NG / CHUNKS)    // 64 gaussians per chunk
#define PPB 64              // pixels per block (one wave's lanes)
#define NACC 13

__device__ __forceinline__ float softplus_f(float x) {
    if (x > 20.0f) return x;
    if (x < -20.0f) return expf(x);
    return log1pf(expf(x));
}

__device__ __forceinline__ float sigmoid_f(float x) {
    return 1.0f / (1.0f + expf(-x));
}

// Per-gaussian params: [mx, my, a, b] [c, opac, r, g] [bcol, 0,0,0] — 3 float4 each.
__global__ void prep_kernel(const float* __restrict__ means,
                            const float* __restrict__ chol,
                            const float* __restrict__ rgbl,
                            const float* __restrict__ opl,
                            float* __restrict__ params) {
    int n = blockIdx.x * blockDim.x + threadIdx.x;
    if (n >= NG) return;
    float L11 = softplus_f(chol[3*n + 0]);
    float L21 = chol[3*n + 1];
    float L22 = softplus_f(chol[3*n + 2]);
    float s00 = L11 * L11;
    float s01 = L11 * L21;
    float s11 = L21 * L21 + L22 * L22;
    float d  = L11 * L22;
    float inv = 1.0f / (d * d);
    float* p = params + 12 * n;
    p[0] = means[2*n + 0];
    p[1] = means[2*n + 1];
    p[2] =  s11 * inv;
    p[3] = -s01 * inv;
    p[4] =  s00 * inv;
    p[5] = sigmoid_f(opl[n]);
    p[6] = sigmoid_f(rgbl[3*n + 0]);
    p[7] = sigmoid_f(rgbl[3*n + 1]);
    p[8] = sigmoid_f(rgbl[3*n + 2]);
    p[9] = 0.0f; p[10] = 0.0f; p[11] = 0.0f;
}

// 512 threads = 8 waves. Wave w handles gaussian chunk w for the block's 64
// pixels (one pixel per lane). Chunked transmittance: all accumulators are
// linear in entry-T, so chunk j's contribution = (prod_{i<j} T_i) * local acc.
// 8 waves/SIMD (32/CU, max) to hide param-load + exp latency that dominated
// the 1-wave/SIMD baseline (447 cy/iter measured vs ~60 issue-bound).
__global__ __launch_bounds__(512, 8)
void render_kernel(const float* __restrict__ params, float* __restrict__ out) {
    const int lane = threadIdx.x & 63;
    const int wv   = threadIdx.x >> 6;        // chunk id 0..7
    const int pixbase = blockIdx.x * PPB;
    const int pix  = pixbase + lane;          // 64 consecutive pixels, same row
    const float px = (float)(pix & (WW - 1)) + 0.5f;
    const float py = (float)(pix >> 8) + 0.5f;

    // wave-uniform param base for this chunk (float4 units); force SGPR.
    const int gofs = __builtin_amdgcn_readfirstlane(wv * CG * 3);
    const float4* __restrict__ g4 = (const float4*)params + gofs;

    float T = 1.0f;
    float ir = 0.f, ig = 0.f, ib = 0.f, wsum = 0.f;
    float xr = 0.f, xg = 0.f, xb = 0.f;
    float yr = 0.f, yg = 0.f, yb = 0.f;
    float qr = 0.f, qg = 0.f, qb = 0.f;

    #pragma unroll 4
    for (int n = 0; n < CG; ++n) {
        float4 P0 = g4[3*n + 0];   // mx, my, a, b
        float4 P1 = g4[3*n + 1];   // c, opac, r, g
        float4 P2 = g4[3*n + 2];   // bcol, -, -, -
        float dX = P0.x - px;
        float dY = P0.y - py;
        float a = P0.z, b = P0.w, c = P1.x, opac = P1.y;
        float gx = a * dX + b * dY;
        float gy = b * dX + c * dY;
        float s  = 0.5f * (dX * gx + dY * gy);
        float e  = __expf(-s);
        float alpha = fminf(opac * e, 0.999f);
        float vis = alpha * T;
        T = T - alpha * T;
        wsum += vis;
        float r = P1.z, g = P1.w, bb = P2.x;
        ir += vis * r;  ig += vis * g;  ib += vis * bb;
        float vgx = vis * gx;
        float vgy = vis * gy;
        xr += vgx * r;  xg += vgx * g;  xb += vgx * bb;
        yr += vgy * r;  yg += vgy * g;  yb += vgy * bb;
        float q  = gx * gy - b;
        float vq = vis * q;
        qr += vq * r;   qg += vq * g;   qb += vq * bb;
    }

    // --- merge chunks across waves via LDS ---
    __shared__ float Tl[CHUNKS][PPB];                 // 2 KB
    __shared__ float accL[NACC][CHUNKS][PPB];         // 26.6 KB
    Tl[wv][lane] = T;
    __syncthreads();

    float scale = 1.0f;
    for (int i = 0; i < wv; ++i) scale *= Tl[i][lane];   // wave-uniform trip count

    // conflict-free writes: for fixed comp, lanes are consecutive addresses
    accL[ 0][wv][lane] = ir   * scale;
    accL[ 1][wv][lane] = ig   * scale;
    accL[ 2][wv][lane] = ib   * scale;
    accL[ 3][wv][lane] = wsum * scale;
    accL[ 4][wv][lane] = xr   * scale;
    accL[ 5][wv][lane] = xg   * scale;
    accL[ 6][wv][lane] = xb   * scale;
    accL[ 7][wv][lane] = yr   * scale;
    accL[ 8][wv][lane] = yg   * scale;
    accL[ 9][wv][lane] = yb   * scale;
    accL[10][wv][lane] = qr   * scale;
    accL[11][wv][lane] = qg   * scale;
    accL[12][wv][lane] = qb   * scale;
    __syncthreads();

    const int HW = HH * WW;
    for (int v = threadIdx.x; v < PPB * NACC; v += 512) {
        int pp   = v / NACC;
        int comp = v - pp * NACC;
        float s = 0.f;
        #pragma unroll
        for (int cch = 0; cch < CHUNKS; ++cch) s += accL[comp][cch][pp];
        int p = pixbase + pp;
        if (comp < 3) {
            out[comp * HW + p] = s;                 // render [c][h][w]
            out[3 * HW + 3 * p + comp] = s;         // img [h][w][c]
        } else if (comp == 3) {
            out[6 * HW + p] = s;                    // wsum
        } else if (comp < 7) {
            out[7 * HW + 3 * p + (comp - 4)] = s;   // dx_img
        } else if (comp < 10) {
            out[10 * HW + 3 * p + (comp - 7)] = s;  // dy_img
        } else {
            out[13 * HW + 3 * p + (comp - 10)] = s; // dxy_img
        }
    }
}

extern "C" void kernel_launch(void* const* d_in, const int* in_sizes, int n_in,
                              void* d_out, int out_size, void* d_ws, size_t ws_size,
                              hipStream_t stream) {
    const float* means = (const float*)d_in[0];
    const float* chol  = (const float*)d_in[1];
    const float* rgbl  = (const float*)d_in[2];
    const float* opl   = (const float*)d_in[3];
    float* out = (float*)d_out;
    float* params = (float*)d_ws;   // 512 * 12 floats = 24 KB

    prep_kernel<<<dim3((NG + 255) / 256), dim3(256), 0, stream>>>(means, chol, rgbl, opl, params);
    render_kernel<<<dim3((HH * WW) / PPB), dim3(512), 0, stream>>>(params, out);
}

// Round 11
// 71.130 us; speedup vs baseline: 2.1532x; 1.2723x over previous
//
#include <hip/hip_runtime.h>
#include <math.h>

#define NG 512
#define HH 256
#define WW 256
#define TILE 8
#define TXN (WW / TILE)      // 32 tiles across
#define TYN (HH / TILE)      // 32 tiles down
#define NTILES (TXN * TYN)   // 1024
#define CHUNKS 8
#define NACC 13
#define S_CUT 12.0f          // skip when sigma > 12: alpha < opac*e^-12 ~ 3e-6

__device__ __forceinline__ float softplus_f(float x) {
    if (x > 20.0f) return x;
    if (x < -20.0f) return expf(x);
    return log1pf(expf(x));
}

__device__ __forceinline__ float sigmoid_f(float x) {
    return 1.0f / (1.0f + expf(-x));
}

// Per-gaussian params: [mx, my, a, b] [c, opac, r, g] [bcol, 0,0,0] — 3 float4.
// Plus conservative tile-index AABB of the {sigma <= S_CUT} ellipse:
// max |dX| on the level set = sqrt(2*S_CUT*Sigma_xx), Sigma_xx = L11^2.
__global__ void prep_kernel(const float* __restrict__ means,
                            const float* __restrict__ chol,
                            const float* __restrict__ rgbl,
                            const float* __restrict__ opl,
                            float* __restrict__ params,
                            int4* __restrict__ tb) {
    int n = blockIdx.x * blockDim.x + threadIdx.x;
    if (n >= NG) return;
    float L11 = softplus_f(chol[3*n + 0]);
    float L21 = chol[3*n + 1];
    float L22 = softplus_f(chol[3*n + 2]);
    float s00 = L11 * L11;                 // Sigma_xx
    float s01 = L11 * L21;
    float s11 = L21 * L21 + L22 * L22;     // Sigma_yy
    float d  = L11 * L22;
    float inv = 1.0f / (d * d);
    float mx = means[2*n + 0];
    float my = means[2*n + 1];
    float* p = params + 12 * n;
    p[0] = mx;
    p[1] = my;
    p[2] =  s11 * inv;
    p[3] = -s01 * inv;
    p[4] =  s00 * inv;
    p[5] = sigmoid_f(opl[n]);
    p[6] = sigmoid_f(rgbl[3*n + 0]);
    p[7] = sigmoid_f(rgbl[3*n + 1]);
    p[8] = sigmoid_f(rgbl[3*n + 2]);
    p[9] = 0.0f; p[10] = 0.0f; p[11] = 0.0f;

    float ex = sqrtf(2.0f * S_CUT * s00);
    float ey = sqrtf(2.0f * S_CUT * s11);
    int4 r;
    r.x = max(0,       (int)floorf((mx - ex) * (1.0f / TILE)));   // tx0
    r.y = min(TXN - 1, (int)floorf((mx + ex) * (1.0f / TILE)));   // tx1
    r.z = max(0,       (int)floorf((my - ey) * (1.0f / TILE)));   // ty0
    r.w = min(TYN - 1, (int)floorf((my + ey) * (1.0f / TILE)));   // ty1
    tb[n] = r;
}

// One block per 8x8 tile; 512 threads = 8 waves; wave w owns gaussian chunk
// [64w, 64w+64). Lane g ballots its gaussian's tile-AABB vs this tile -> 64-bit
// survivor mask; ctz iteration preserves front-to-back order exactly.
// Chunked transmittance merge as before (accumulators linear in entry-T).
__global__ __launch_bounds__(512, 8)
void render_kernel(const float* __restrict__ params,
                   const int4* __restrict__ tb,
                   float* __restrict__ out) {
    const int lane = threadIdx.x & 63;
    const int wv   = threadIdx.x >> 6;         // chunk id 0..7
    const int tx   = blockIdx.x & (TXN - 1);
    const int ty   = blockIdx.x >> 5;
    const int x0   = tx * TILE;
    const int y0   = ty * TILE;
    const float px = (float)(x0 + (lane & 7)) + 0.5f;
    const float py = (float)(y0 + (lane >> 3)) + 0.5f;

    // build this wave's survivor mask: lane g tests gaussian wv*64+g
    int4 bb = tb[threadIdx.x];
    bool hit = (tx >= bb.x) && (tx <= bb.y) && (ty >= bb.z) && (ty <= bb.w);
    unsigned long long m = __ballot(hit ? 1 : 0);

    const float4* __restrict__ g4 = (const float4*)params;
    const int cbase = wv * 64;

    float T = 1.0f;
    float ir = 0.f, ig = 0.f, ib = 0.f, wsum = 0.f;
    float xr = 0.f, xg = 0.f, xb = 0.f;
    float yr = 0.f, yg = 0.f, yb = 0.f;
    float qr = 0.f, qg = 0.f, qb = 0.f;

    while (m) {
        int n = __builtin_ctzll(m);
        m &= (m - 1);
        int gi = __builtin_amdgcn_readfirstlane(cbase + n);  // wave-uniform index
        float4 P0 = g4[3*gi + 0];   // mx, my, a, b
        float4 P1 = g4[3*gi + 1];   // c, opac, r, g
        float4 P2 = g4[3*gi + 2];   // bcol, -, -, -
        float dX = P0.x - px;
        float dY = P0.y - py;
        float a = P0.z, b = P0.w, c = P1.x, opac = P1.y;
        float gx = a * dX + b * dY;
        float gy = b * dX + c * dY;
        float s  = 0.5f * (dX * gx + dY * gy);
        float e  = __expf(-s);
        float alpha = fminf(opac * e, 0.999f);
        float vis = alpha * T;
        T = T - alpha * T;
        wsum += vis;
        float r = P1.z, g = P1.w, bcol = P2.x;
        ir += vis * r;  ig += vis * g;  ib += vis * bcol;
        float vgx = vis * gx;
        float vgy = vis * gy;
        xr += vgx * r;  xg += vgx * g;  xb += vgx * bcol;
        yr += vgy * r;  yg += vgy * g;  yb += vgy * bcol;
        float q  = gx * gy - b;
        float vq = vis * q;
        qr += vq * r;   qg += vq * g;   qb += vq * bcol;
    }

    // --- merge chunks across waves via LDS (28.6 KB/block) ---
    __shared__ float Tl[CHUNKS][64];
    __shared__ float accL[NACC][CHUNKS][64];
    Tl[wv][lane] = T;
    __syncthreads();

    float scale = 1.0f;
    for (int i = 0; i < wv; ++i) scale *= Tl[i][lane];  // wave-uniform trip count

    accL[ 0][wv][lane] = ir   * scale;
    accL[ 1][wv][lane] = ig   * scale;
    accL[ 2][wv][lane] = ib   * scale;
    accL[ 3][wv][lane] = wsum * scale;
    accL[ 4][wv][lane] = xr   * scale;
    accL[ 5][wv][lane] = xg   * scale;
    accL[ 6][wv][lane] = xb   * scale;
    accL[ 7][wv][lane] = yr   * scale;
    accL[ 8][wv][lane] = yg   * scale;
    accL[ 9][wv][lane] = yb   * scale;
    accL[10][wv][lane] = qr   * scale;
    accL[11][wv][lane] = qg   * scale;
    accL[12][wv][lane] = qb   * scale;
    __syncthreads();

    const int HW = HH * WW;
    for (int v = threadIdx.x; v < 64 * NACC; v += 512) {
        int pp   = v / NACC;
        int comp = v - pp * NACC;
        float s = 0.f;
        #pragma unroll
        for (int cch = 0; cch < CHUNKS; ++cch) s += accL[comp][cch][pp];
        int p = (y0 + (pp >> 3)) * WW + x0 + (pp & 7);
        if (comp < 3) {
            out[comp * HW + p] = s;                 // render [c][h][w]
            out[3 * HW + 3 * p + comp] = s;         // img [h][w][c]
        } else if (comp == 3) {
            out[6 * HW + p] = s;                    // wsum
        } else if (comp < 7) {
            out[7 * HW + 3 * p + (comp - 4)] = s;   // dx_img
        } else if (comp < 10) {
            out[10 * HW + 3 * p + (comp - 7)] = s;  // dy_img
        } else {
            out[13 * HW + 3 * p + (comp - 10)] = s; // dxy_img
        }
    }
}

extern "C" void kernel_launch(void* const* d_in, const int* in_sizes, int n_in,
                              void* d_out, int out_size, void* d_ws, size_t ws_size,
                              hipStream_t stream) {
    const float* means = (const float*)d_in[0];
    const float* chol  = (const float*)d_in[1];
    const float* rgbl  = (const float*)d_in[2];
    const float* opl   = (const float*)d_in[3];
    float* out = (float*)d_out;
    float* params = (float*)d_ws;                       // 512*12 floats = 24 KB
    int4*  tb     = (int4*)((char*)d_ws + 24 * 1024);   // 512*16 B = 8 KB

    prep_kernel<<<dim3(2), dim3(256), 0, stream>>>(means, chol, rgbl, opl, params, tb);
    render_kernel<<<dim3(NTILES), dim3(512), 0, stream>>>(params, tb, out);
}